// Round 7
// baseline (76.046 us; speedup 1.0000x reference)
//
#include <hip/hip_runtime.h>

// YOLO decode = batched [255 x 5776] transpose + elementwise.
// B=32, A=3, C=80 -> attrs=85, CH=255, G=76, SP=5776, stride=8.
// R7: software-pipelined persistent blocks. 512 blocks (2/CU), each grid-strides
//     over 32-wide tiles with double-buffered LDS (2x32640B) + register prefetch:
//     decode(k)->buf[k&1]; issue loads(k+1)->regs; barrier; nt-store buf[k&1].
//     One barrier per tile; loads in flight across it (reg-dest, not LDS-dest).

#define BATCH   32
#define ATTRS   85
#define CH      255
#define GRID    76
#define SP      5776          // 76*76; tiles: 180 full 32-wide + one 16-wide per batch
#define STRIDE_F 8.0f
#define S_TILE  32
#define TPB     1024
#define TILES_PER_B 181
#define NTILES  (BATCH * TILES_PER_B)   // 5792
#define NBLK    512                     // 2 blocks/CU resident
#define NF4     (CH * (S_TILE / 4))     // 2040 f4 per tile

typedef float f4 __attribute__((ext_vector_type(4)));

__device__ __forceinline__ float decode1(float val, int attr, int s,
                                         float ax, float ay) {
    if (attr == 2) return __expf(val) * ax;
    if (attr == 3) return __expf(val) * ay;
    const float sg = __builtin_amdgcn_rcpf(1.0f + __expf(-val));
    if (attr == 0) return (sg + (float)(s % GRID)) * STRIDE_F;
    if (attr == 1) return (sg + (float)(s / GRID)) * STRIDE_F;
    return sg;
}

__global__ __launch_bounds__(TPB, 8) void yolo_decode_kernel(
        const float* __restrict__ pred,
        const float* __restrict__ anchors,
        float* __restrict__ out) {
    __shared__ float buf[2][S_TILE * CH];   // 65280 B total

    const int tid = threadIdx.x;

    const float a0x = anchors[0], a0y = anchors[1];
    const float a1x = anchors[2], a1y = anchors[3];
    const float a2x = anchors[4], a2y = anchors[5];

    // fixed per-thread (channel, spatial-chunk) pairs; conflict-free scatter:
    // 32-lane group = 4 channels x 8 chunks -> banks (c - 4k - e) cover all 32.
    const int c0  = tid >> 3;            // 0..127
    const int sl0 = (tid & 7) * 4;
    const int j1  = tid + TPB;
    const int c1  = j1 >> 3;             // 128..255
    const int sl1 = (j1 & 7) * 4;
    const bool have1 = (j1 < NF4);       // tid < 1016  ->  c1 <= 254

    const int aI0 = c0 / ATTRS, attr0 = c0 - aI0 * ATTRS;
    const int aI1 = c1 / ATTRS, attr1 = c1 - aI1 * ATTRS;
    const float ax0 = (aI0 == 0) ? a0x : (aI0 == 1) ? a1x : a2x;
    const float ay0 = (aI0 == 0) ? a0y : (aI0 == 1) ? a1y : a2y;
    const float ax1 = (aI1 == 0) ? a0x : (aI1 == 1) ? a1x : a2x;
    const float ay1 = (aI1 == 0) ? a0y : (aI1 == 1) ? a1y : a2y;

    // ---- prologue: issue loads for this block's first tile ----
    int tk = blockIdx.x;                 // < 512 < NTILES always
    int b  = tk / TILES_PER_B;
    int t  = tk - b * TILES_PER_B;
    int s0 = t * S_TILE;
    int sw = (t == TILES_PER_B - 1) ? (SP - s0) : S_TILE;   // 16 on last tile
    const float* src = pred + (size_t)b * ((size_t)CH * SP) + s0;

    f4 v0 = {0.f, 0.f, 0.f, 0.f}, v1 = {0.f, 0.f, 0.f, 0.f};
    if (sl0 < sw)          v0 = *(const f4*)(src + (size_t)c0 * SP + sl0);
    if (have1 && sl1 < sw) v1 = *(const f4*)(src + (size_t)c1 * SP + sl1);

    int it = 0;
    for (;;) {
        float* __restrict__ B = buf[it & 1];
        const int cb = b, cs0 = s0, csw = sw;   // params of the tile in regs

        // ---- decode current tile regs -> LDS (vmcnt wait happens here) ----
        #pragma unroll
        for (int e = 0; e < 4; ++e)
            B[(sl0 + e) * CH + c0] = decode1(v0[e], attr0, cs0 + sl0 + e, ax0, ay0);
        if (have1) {
            #pragma unroll
            for (int e = 0; e < 4; ++e)
                B[(sl1 + e) * CH + c1] = decode1(v1[e], attr1, cs0 + sl1 + e, ax1, ay1);
        }

        // ---- issue next tile's loads (stay in flight across the barrier) ----
        const int ntk = tk + NBLK;
        const bool more = (ntk < NTILES);
        if (more) {
            b  = ntk / TILES_PER_B;
            t  = ntk - b * TILES_PER_B;
            s0 = t * S_TILE;
            sw = (t == TILES_PER_B - 1) ? (SP - s0) : S_TILE;
            src = pred + (size_t)b * ((size_t)CH * SP) + s0;
            if (sl0 < sw)          v0 = *(const f4*)(src + (size_t)c0 * SP + sl0);
            if (have1 && sl1 < sw) v1 = *(const f4*)(src + (size_t)c1 * SP + sl1);
        }

        __syncthreads();   // buf[it&1] fully decoded; also fences prior store phase

        // ---- store phase: contiguous [csw*255] floats, nontemporal ----
        const float* __restrict__ Bs = buf[it & 1];
        float* __restrict__ dst = out + (size_t)cb * ((size_t)SP * CH)
                                      + (size_t)cs0 * CH;
        const int nf4w = (csw * CH) >> 2;    // 2040 full, 1020 partial
        for (int j = tid; j < nf4w; j += TPB) {
            f4 w = *(const f4*)(Bs + j * 4);
            __builtin_nontemporal_store(w, (f4*)(dst + j * 4));
        }

        if (!more) break;
        tk = ntk;
        ++it;
    }
}

extern "C" void kernel_launch(void* const* d_in, const int* in_sizes, int n_in,
                              void* d_out, int out_size, void* d_ws, size_t ws_size,
                              hipStream_t stream) {
    const float* pred    = (const float*)d_in[0];
    const float* anchors = (const float*)d_in[1];
    float* out = (float*)d_out;

    yolo_decode_kernel<<<NBLK, TPB, 0, stream>>>(pred, anchors, out);
}